// Round 8
// baseline (247.536 us; speedup 1.0000x reference)
//
#include <hip/hip_runtime.h>
#include <hip/hip_bf16.h>
#include <stdint.h>

#define NROWS   65536
#define RPB     64
#define NBLK    (NROWS/RPB)       // 1024
#define H2N     100
#define KPAD    128
#define N3      1224
#define OUTW    2193
#define TAILN   969
#define T1OFF   77
#define NTILE   138               // 77 main + 61 pair logical tiles
#define NTOT    199               // frag tiles in w3f
#define NPANEL  18                // 18 panels x 8 slots = 144 slots (138 real + 6 pad)
#define PSTR    132               // f32 row stride of LDS panel

typedef __attribute__((ext_vector_type(8))) short bf16x8;
typedef __attribute__((ext_vector_type(4))) float f32x4;

__device__ __forceinline__ float fast_sigmoid(float z){
    return __builtin_amdgcn_rcpf(1.0f + __expf(-z));
}
__device__ __forceinline__ unsigned short f2bf(float v){
    __hip_bfloat16 h = __float2bfloat16(v);
    return *reinterpret_cast<unsigned short*>(&h);
}
__device__ __forceinline__ void store16(float* p, f32x4 v){
    __builtin_memcpy(p, &v, 16);
}

// Build fragment-ordered extended B: w3f[((t*4+ks)*64+lane)*8 + e]
//   = bf16( W3[k=ks*32+(lane>>4)*8+e][ srccol(t, lane&15) ] ), zero-padded.
// frag tiles: 0..76 main cols; 77..137 gathered c1; 138..198 gathered c2.
__global__ void prep_kernel(const float* __restrict__ W3,
                            const float* __restrict__ b3,
                            const float* __restrict__ wgt,
                            const int* __restrict__ idx1,
                            const int* __restrict__ idx2,
                            unsigned short* __restrict__ w3f,
                            float* __restrict__ b3f,
                            float* __restrict__ pwf){
    const int t    = blockIdx.x;            // one frag tile per block
    const int ks   = threadIdx.x >> 6;
    const int lane = threadIdx.x & 63;
    const int lm   = lane & 15, lgf = lane >> 4;

    int col = -1;
    if (t < T1OFF){
        int c = t * 16 + lm;
        if (c < N3) col = c;
    } else if (t < NTILE){
        int p = (t - T1OFF) * 16 + lm;
        if (p < TAILN){ int j = p / 17; col = idx1[j] * 17 + (p - j * 17); }
    } else {
        int p = (t - NTILE) * 16 + lm;
        if (p < TAILN){ int j = p / 17; col = idx2[j] * 17 + (p - j * 17); }
    }

    unsigned short vals[8];
    #pragma unroll
    for (int e = 0; e < 8; ++e){
        int k = ks * 32 + lgf * 8 + e;
        float v = (col >= 0 && k < H2N) ? W3[k * N3 + col] : 0.0f;
        vals[e] = f2bf(v);
    }
    *reinterpret_cast<bf16x8*>(w3f + ((size_t)(t * 4 + ks) * 64 + lane) * 8)
        = *reinterpret_cast<bf16x8*>(vals);

    if (ks == 0 && lgf == 0)
        b3f[t * 16 + lm] = (col >= 0) ? b3[col] : 0.0f;
    if (ks == 0 && lgf == 1 && t >= T1OFF && t < NTILE){
        int p = (t - T1OFF) * 16 + lm;
        if (p < TAILN) pwf[p] = wgt[p / 17];
    }
}

__global__ __launch_bounds__(256, 3)
void snn_kernel(const float* __restrict__ x,
                const float* __restrict__ W1, const float* __restrict__ b1,
                const float* __restrict__ W2, const float* __restrict__ b2,
                const unsigned short* __restrict__ w3f,
                const float* __restrict__ b3f,
                const float* __restrict__ pwf,
                float* __restrict__ out)
{
    __shared__ __align__(16) unsigned short lds_h2[RPB][KPAD];   // 16 KB
    __shared__ float lds_h1[RPB][10];                            // 2.5 KB
    __shared__ __align__(16) float lds_p[RPB][PSTR];             // 33.8 KB

    const int t    = threadIdx.x;
    const int row0 = blockIdx.x * RPB;

    // ---- layer 1
    for (int i = t; i < RPB * 10; i += 256){
        int r = i / 10, j = i - r * 10;
        lds_h1[r][j] = fast_sigmoid(x[row0 + r] * W1[j] + b1[j]);
    }
    __syncthreads();

    // ---- layer 2 -> bf16 LDS (k 100..127 zero-padded)
    for (int i = t; i < RPB * KPAD; i += 256){
        int r = i >> 7, c = i & 127;
        float v = 0.0f;
        if (c < H2N){
            float z = b2[c];
            #pragma unroll
            for (int j = 0; j < 10; ++j) z += lds_h1[r][j] * W2[j * H2N + c];
            v = fast_sigmoid(z);
        }
        lds_h2[r][c] = f2bf(v);
    }
    __syncthreads();

    // ---- layer 3 + tail via MFMA; A = W3-tile (rows = out cols), B = h2 (cols = out rows)
    const int lane = t & 63, wid = t >> 6;
    const int lm = lane & 15, lg = lane >> 4;

    bf16x8 hfr[4][4];   // 4 row-tiles x 4 k-steps (64 VGPR)
    #pragma unroll
    for (int rt = 0; rt < 4; ++rt)
        #pragma unroll
        for (int ks = 0; ks < 4; ++ks)
            hfr[rt][ks] = *reinterpret_cast<const bf16x8*>(&lds_h2[rt * 16 + lm][ks * 32 + lg * 8]);

    #define LOADFRAG(dst, tile) do {                                              \
        const unsigned short* bp_ = w3f + ((size_t)((tile) * 4) * 64 + lane) * 8; \
        _Pragma("unroll")                                                         \
        for (int ks_ = 0; ks_ < 4; ++ks_)                                         \
            dst[ks_] = *reinterpret_cast<const bf16x8*>(bp_ + (size_t)ks_ * 512); \
    } while(0)
    #define CPFRAG(d, s) do { _Pragma("unroll") for (int k_=0;k_<4;++k_) d[k_]=s[k_]; } while(0)

    auto MFMA16 = [&](bf16x8 (&cf)[4], f32x4 (&acc)[4]){
        #pragma unroll
        for (int rt = 0; rt < 4; ++rt) acc[rt] = f32x4{0,0,0,0};
        #pragma unroll
        for (int ks = 0; ks < 4; ++ks)
            #pragma unroll
            for (int rt = 0; rt < 4; ++rt)
                acc[rt] = __builtin_amdgcn_mfma_f32_16x16x32_bf16(cf[ks], hfr[rt][ks], acc[rt], 0, 0, 0);
    };
    auto EPI_MAIN = [&](int s, int pc, f32x4 (&acc)[4]){
        const f32x4 bv = *reinterpret_cast<const f32x4*>(b3f + s * 16 + lg * 4);
        #pragma unroll
        for (int rt = 0; rt < 4; ++rt){
            f32x4 v;
            #pragma unroll
            for (int r = 0; r < 4; ++r) v[r] = fast_sigmoid(acc[rt][r] + bv[r]);
            *reinterpret_cast<f32x4*>(&lds_p[rt * 16 + lm][pc]) = v;
        }
    };
    auto EPI_PA = [&](int s, int pc, f32x4 (&acc)[4]){        // panel = w*sig(u1)
        const f32x4 bv = *reinterpret_cast<const f32x4*>(b3f + s * 16 + lg * 4);
        const f32x4 wv = *reinterpret_cast<const f32x4*>(pwf + (s - T1OFF) * 16 + lg * 4);
        #pragma unroll
        for (int rt = 0; rt < 4; ++rt){
            f32x4 v;
            #pragma unroll
            for (int r = 0; r < 4; ++r) v[r] = wv[r] * fast_sigmoid(acc[rt][r] + bv[r]);
            *reinterpret_cast<f32x4*>(&lds_p[rt * 16 + lm][pc]) = v;
        }
    };
    auto EPI_PB = [&](int s61, int pc, f32x4 (&acc)[4]){      // panel += (1-w)*sig(u2)
        const f32x4 bv = *reinterpret_cast<const f32x4*>(b3f + s61 * 16 + lg * 4);
        const f32x4 wv = *reinterpret_cast<const f32x4*>(pwf + (s61 - NTILE) * 16 + lg * 4);
        #pragma unroll
        for (int rt = 0; rt < 4; ++rt){
            f32x4 v = *reinterpret_cast<const f32x4*>(&lds_p[rt * 16 + lm][pc]);
            #pragma unroll
            for (int r = 0; r < 4; ++r)
                v[r] = fmaf(1.0f - wv[r], fast_sigmoid(acc[rt][r] + bv[r]), v[r]);
            *reinterpret_cast<f32x4*>(&lds_p[rt * 16 + lm][pc]) = v;
        }
    };

    const int l5 = lane & 31, lh = lane >> 5;

    for (int p = 0; p < NPANEL; ++p){
        const int sb = p * 8;
        const int sA = sb + wid, sB = sA + 4;
        const int pcA = wid * 16 + lg * 4, pcB = pcA + 64;
        const bool vA = (sA < NTILE), vB = (sB < NTILE);

        bf16x8 cf[4], nf[4];
        if (vA){
            LOADFRAG(cf, sA);
            if (sA < T1OFF){                       // main slot A
                if (vB) LOADFRAG(nf, sB);
                f32x4 acc[4]; MFMA16(cf, acc); EPI_MAIN(sA, pcA, acc);
                if (vB) CPFRAG(cf, nf);
            } else {                               // pair slot A
                LOADFRAG(nf, sA + 61);
                f32x4 acc[4]; MFMA16(cf, acc); EPI_PA(sA, pcA, acc);
                CPFRAG(cf, nf);
                if (vB) LOADFRAG(nf, sB);
                f32x4 acc2[4]; MFMA16(cf, acc2); EPI_PB(sA + 61, pcA, acc2);
                if (vB) CPFRAG(cf, nf);
            }
        }
        if (vB){
            if (sB < T1OFF){                       // main slot B
                f32x4 acc[4]; MFMA16(cf, acc); EPI_MAIN(sB, pcB, acc);
            } else {                               // pair slot B
                LOADFRAG(nf, sB + 61);
                f32x4 acc[4]; MFMA16(cf, acc); EPI_PA(sB, pcB, acc);
                CPFRAG(cf, nf);
                f32x4 acc2[4]; MFMA16(cf, acc2); EPI_PB(sB + 61, pcB, acc2);
            }
        }
        __syncthreads();

        // -------- dump panel: 2 rows x 512B contiguous per store iteration
        const int vb = p * 128 + l5 * 4;           // virtual col base for this lane
        int mode = 0, real = 0;
        if (vb <= 1220)                    { mode = 1; real = vb; }
        else if (vb >= 1232 && vb <= 2196) { mode = 1; real = vb - 8; }
        else if (vb == 2200)               { mode = 2; real = 2192; }

        #pragma unroll
        for (int rr = 0; rr < 8; ++rr){
            const int row = wid * 16 + rr * 2 + lh;
            f32x4 v = *reinterpret_cast<const f32x4*>(&lds_p[row][l5 * 4]);
            const unsigned int off = (unsigned int)(row0 + row) * OUTW + real;
            if (mode == 1)      store16(out + off, v);
            else if (mode == 2) out[off] = v[0];
        }
        __syncthreads();
    }
    #undef LOADFRAG
    #undef CPFRAG
}

extern "C" void kernel_launch(void* const* d_in, const int* in_sizes, int n_in,
                              void* d_out, int out_size, void* d_ws, size_t ws_size,
                              hipStream_t stream)
{
    const float* x   = (const float*)d_in[0];
    const float* W1  = (const float*)d_in[1];
    const float* b1  = (const float*)d_in[2];
    const float* W2  = (const float*)d_in[3];
    const float* b2  = (const float*)d_in[4];
    const float* W3  = (const float*)d_in[5];
    const float* b3  = (const float*)d_in[6];
    const float* wgt = (const float*)d_in[7];
    const int*   i1  = (const int*)d_in[8];
    const int*   i2  = (const int*)d_in[9];
    float* out = (float*)d_out;

    unsigned char* ws = (unsigned char*)d_ws;
    unsigned short* w3f = (unsigned short*)ws;                 // 199*4*64*8*2 = 815,104 B
    float*          b3f = (float*)(ws + 815104);               // 3184*4 = 12,736 B
    float*          pwf = (float*)(ws + 815104 + 12736);       // 976*4  =  3,904 B

    prep_kernel<<<NTOT, 256, 0, stream>>>(W3, b3, wgt, i1, i2, w3f, b3f, pwf);
    snn_kernel<<<NBLK, 256, 0, stream>>>(x, W1, b1, W2, b2, w3f, b3f, pwf, out);
}

// Round 9
// 234.603 us; speedup vs baseline: 1.0551x; 1.0551x over previous
//
#include <hip/hip_runtime.h>
#include <hip/hip_bf16.h>
#include <stdint.h>

#define NROWS   65536
#define RPB     32
#define NBLK    (NROWS/RPB)       // 2048
#define H2N     100
#define KPAD    128
#define N3      1224
#define OUTW    2193
#define TAILN   969
#define T1OFF   77
#define NTILE   138               // 77 main + 61 pair logical slots
#define NTOT    199               // frag tiles in w3f
#define NPANEL  18                // 18 panels x 8 slots
#define PSTR    132               // f32 row stride of LDS panel

typedef __attribute__((ext_vector_type(8))) short bf16x8;
typedef __attribute__((ext_vector_type(4))) float f32x4;

__device__ __forceinline__ float fast_sigmoid(float z){
    return __builtin_amdgcn_rcpf(1.0f + __expf(-z));
}
__device__ __forceinline__ unsigned short f2bf(float v){
    __hip_bfloat16 h = __float2bfloat16(v);
    return *reinterpret_cast<unsigned short*>(&h);
}
__device__ __forceinline__ void store16(float* p, f32x4 v){
    __builtin_memcpy(p, &v, 16);
}

// w3f[((t*4+ks)*64+lane)*8+e] = bf16(W3[k=ks*32+(lane>>4)*8+e][srccol(t,lane&15)])
// frag tiles: 0..76 main; 77..137 gathered c1; 138..198 gathered c2.
__global__ void prep_kernel(const float* __restrict__ W3,
                            const float* __restrict__ b3,
                            const float* __restrict__ wgt,
                            const int* __restrict__ idx1,
                            const int* __restrict__ idx2,
                            unsigned short* __restrict__ w3f,
                            float* __restrict__ b3f,
                            float* __restrict__ pwf){
    const int t    = blockIdx.x;
    const int ks   = threadIdx.x >> 6;
    const int lane = threadIdx.x & 63;
    const int lm   = lane & 15, lgf = lane >> 4;

    int col = -1;
    if (t < T1OFF){
        int c = t * 16 + lm;
        if (c < N3) col = c;
    } else if (t < NTILE){
        int p = (t - T1OFF) * 16 + lm;
        if (p < TAILN){ int j = p / 17; col = idx1[j] * 17 + (p - j * 17); }
    } else {
        int p = (t - NTILE) * 16 + lm;
        if (p < TAILN){ int j = p / 17; col = idx2[j] * 17 + (p - j * 17); }
    }

    unsigned short vals[8];
    #pragma unroll
    for (int e = 0; e < 8; ++e){
        int k = ks * 32 + lgf * 8 + e;
        float v = (col >= 0 && k < H2N) ? W3[k * N3 + col] : 0.0f;
        vals[e] = f2bf(v);
    }
    *reinterpret_cast<bf16x8*>(w3f + ((size_t)(t * 4 + ks) * 64 + lane) * 8)
        = *reinterpret_cast<bf16x8*>(vals);

    if (ks == 0 && lgf == 0)
        b3f[t * 16 + lm] = (col >= 0) ? b3[col] : 0.0f;
    if (ks == 0 && lgf == 1 && t >= T1OFF && t < NTILE){
        int p = (t - T1OFF) * 16 + lm;
        pwf[(t - T1OFF) * 16 + lm] = (p < TAILN) ? wgt[p / 17] : 0.0f;
    }
}

__global__ __launch_bounds__(256, 3)
void snn_kernel(const float* __restrict__ x,
                const float* __restrict__ W1, const float* __restrict__ b1,
                const float* __restrict__ W2, const float* __restrict__ b2,
                const unsigned short* __restrict__ w3f,
                const float* __restrict__ b3f,
                const float* __restrict__ pwf,
                float* __restrict__ out)
{
    __shared__ __align__(16) unsigned short lds_h2[RPB][KPAD];   // 8 KB
    __shared__ float lds_h1[RPB][10];                            // 1.25 KB
    __shared__ __align__(16) float lds_p[2][RPB][PSTR];          // 33.8 KB (double-buffered)

    const int t    = threadIdx.x;
    const int row0 = blockIdx.x * RPB;

    // ---- layer 1
    for (int i = t; i < RPB * 10; i += 256){
        int r = i / 10, j = i - r * 10;
        lds_h1[r][j] = fast_sigmoid(x[row0 + r] * W1[j] + b1[j]);
    }
    __syncthreads();

    // ---- layer 2 -> bf16 LDS (k 100..127 zero-padded)
    for (int i = t; i < RPB * KPAD; i += 256){
        int r = i >> 7, c = i & 127;
        float v = 0.0f;
        if (c < H2N){
            float z = b2[c];
            #pragma unroll
            for (int j = 0; j < 10; ++j) z += lds_h1[r][j] * W2[j * H2N + c];
            v = fast_sigmoid(z);
        }
        lds_h2[r][c] = f2bf(v);
    }
    __syncthreads();

    const int lane = t & 63, wid = t >> 6;
    const int lm = lane & 15, lg = lane >> 4;
    const int l5 = lane & 31, lh = lane >> 5;

    bf16x8 hfr[2][4];
    #pragma unroll
    for (int rt = 0; rt < 2; ++rt)
        #pragma unroll
        for (int ks = 0; ks < 4; ++ks)
            hfr[rt][ks] = *reinterpret_cast<const bf16x8*>(&lds_h2[rt * 16 + lm][ks * 32 + lg * 8]);

    #define LOADFRAG(dst, tile) do {                                              \
        const unsigned short* bp_ = w3f + ((size_t)((tile) * 4) * 64 + lane) * 8; \
        _Pragma("unroll")                                                         \
        for (int ks_ = 0; ks_ < 4; ++ks_)                                         \
            dst[ks_] = *reinterpret_cast<const bf16x8*>(bp_ + (size_t)ks_ * 512); \
    } while(0)

    auto MFMA8 = [&](bf16x8 (&cf)[4], f32x4 (&acc)[2]){
        acc[0] = f32x4{0,0,0,0}; acc[1] = f32x4{0,0,0,0};
        #pragma unroll
        for (int ks = 0; ks < 4; ++ks)
            #pragma unroll
            for (int rt = 0; rt < 2; ++rt)
                acc[rt] = __builtin_amdgcn_mfma_f32_16x16x32_bf16(cf[ks], hfr[rt][ks], acc[rt], 0, 0, 0);
    };

    // prefetch slot-A frags of a panel into registers (issued early, consumed after barrier)
    auto PREFETCH = [&](int p, bf16x8 (&f1)[4], bf16x8 (&f2)[4]){
        const int sA = p * 8 + wid;
        if (sA < NTILE){
            LOADFRAG(f1, sA);
            if (sA >= T1OFF) LOADFRAG(f2, sA + 61);
        }
    };

    auto DO_SLOT = [&](int s, int pc, int buf, bf16x8 (&f1)[4], bf16x8 (&f2)[4], bool pre){
        if (s >= NTILE) return;
        if (!pre){
            LOADFRAG(f1, s);
            if (s >= T1OFF) LOADFRAG(f2, s + 61);
        }
        f32x4 a1[2];
        MFMA8(f1, a1);
        if (s < T1OFF){
            const f32x4 bv = *reinterpret_cast<const f32x4*>(b3f + s * 16 + lg * 4);
            #pragma unroll
            for (int rt = 0; rt < 2; ++rt){
                f32x4 v;
                #pragma unroll
                for (int r = 0; r < 4; ++r) v[r] = fast_sigmoid(a1[rt][r] + bv[r]);
                *reinterpret_cast<f32x4*>(&lds_p[buf][rt * 16 + lm][pc]) = v;
            }
        } else {
            f32x4 a2[2];
            MFMA8(f2, a2);
            const f32x4 bv1 = *reinterpret_cast<const f32x4*>(b3f + s * 16 + lg * 4);
            const f32x4 bv2 = *reinterpret_cast<const f32x4*>(b3f + (s + 61) * 16 + lg * 4);
            const f32x4 wv  = *reinterpret_cast<const f32x4*>(pwf + (s - T1OFF) * 16 + lg * 4);
            #pragma unroll
            for (int rt = 0; rt < 2; ++rt){
                f32x4 v;
                #pragma unroll
                for (int r = 0; r < 4; ++r){
                    float u1 = fast_sigmoid(a1[rt][r] + bv1[r]);
                    float u2 = fast_sigmoid(a2[rt][r] + bv2[r]);
                    v[r] = fmaf(wv[r], u1 - u2, u2);
                }
                *reinterpret_cast<f32x4*>(&lds_p[buf][rt * 16 + lm][pc]) = v;
            }
        }
    };

    auto COMPUTE_PANEL = [&](int p, bf16x8 (&pf1)[4], bf16x8 (&pf2)[4]){
        const int buf = p & 1;
        const int sA = p * 8 + wid, sB = sA + 4;
        const int pcA = wid * 16 + lg * 4, pcB = pcA + 64;
        DO_SLOT(sA, pcA, buf, pf1, pf2, true);
        bf16x8 g1[4], g2[4];
        DO_SLOT(sB, pcB, buf, g1, g2, false);
    };

    auto DUMP = [&](int p){
        const int buf = p & 1;
        const int vb = p * 128 + l5 * 4;       // virtual col base
        int mode = 0, real = 0;
        if (vb <= 1220)                    { mode = 1; real = vb; }
        else if (vb >= 1232 && vb <= 2196) { mode = 1; real = vb - 8; }
        else if (vb == 2200)               { mode = 2; real = 2192; }
        #pragma unroll
        for (int rr = 0; rr < 4; ++rr){
            const int row = wid * 8 + rr * 2 + lh;
            f32x4 v = *reinterpret_cast<const f32x4*>(&lds_p[buf][row][l5 * 4]);
            const unsigned int off = (unsigned int)(row0 + row) * OUTW + real;
            if (mode == 1)      store16(out + off, v);
            else if (mode == 2) out[off] = v[0];
        }
    };

    // ---- pipelined panel loop: barrier drains stores issued one compute-phase earlier
    bf16x8 pf1[4], pf2[4];
    PREFETCH(0, pf1, pf2);
    COMPUTE_PANEL(0, pf1, pf2);
    for (int p = 0; p < NPANEL; ++p){
        if (p + 1 < NPANEL) PREFETCH(p + 1, pf1, pf2);   // loads issued BEFORE dump's stores
        __syncthreads();                                  // panel p ready; drains dump(p-1) stores
        DUMP(p);                                          // fire-and-forget stores
        if (p + 1 < NPANEL) COMPUTE_PANEL(p + 1, pf1, pf2); // overlaps store drain
    }
    #undef LOADFRAG
}

extern "C" void kernel_launch(void* const* d_in, const int* in_sizes, int n_in,
                              void* d_out, int out_size, void* d_ws, size_t ws_size,
                              hipStream_t stream)
{
    const float* x   = (const float*)d_in[0];
    const float* W1  = (const float*)d_in[1];
    const float* b1  = (const float*)d_in[2];
    const float* W2  = (const float*)d_in[3];
    const float* b2  = (const float*)d_in[4];
    const float* W3  = (const float*)d_in[5];
    const float* b3  = (const float*)d_in[6];
    const float* wgt = (const float*)d_in[7];
    const int*   i1  = (const int*)d_in[8];
    const int*   i2  = (const int*)d_in[9];
    float* out = (float*)d_out;

    unsigned char* ws = (unsigned char*)d_ws;
    unsigned short* w3f = (unsigned short*)ws;                 // 815,104 B
    float*          b3f = (float*)(ws + 815104);               // 12,736 B
    float*          pwf = (float*)(ws + 815104 + 12736);       // 3,904 B

    prep_kernel<<<NTOT, 256, 0, stream>>>(W3, b3, wgt, i1, i2, w3f, b3f, pwf);
    snn_kernel<<<NBLK, 256, 0, stream>>>(x, W1, b1, W2, b2, w3f, b3f, pwf, out);
}